// Round 2
// baseline (1128.150 us; speedup 1.0000x reference)
//
#include <hip/hip_runtime.h>
#include <math.h>

#define N_NODES 100000
#define N_EDGES 1600000
#define IN_CH 128
#define HEADS 4
#define HEAD_DIM 16
#define OUT_CH 64          // HEADS * HEAD_DIM
#define NEG_SLOPE 0.2f
#define EPS 1e-8f

// Kernel 1: h = x @ W.T  (+ fused per-node attention-logit halves)
// block = 256 threads = 4 nodes x 64 channels; grid = 100000/4 = 25000
__global__ __launch_bounds__(256) void gemm_alpha_kernel(
    const float* __restrict__ x,      // [N_NODES, 128]
    const float* __restrict__ W,      // [64, 128]
    const float* __restrict__ a,      // [1, 4, 32]
    float* __restrict__ h,            // [N_NODES, 64]
    float* __restrict__ alpha_src,    // [N_NODES, 4]
    float* __restrict__ alpha_dst)    // [N_NODES, 4]
{
    const int tid = threadIdx.x;
    const int ch = tid & 63;          // output channel 0..63
    const int local_node = tid >> 6;  // 0..3 (one wave per node)
    const int node = blockIdx.x * 4 + local_node;

    __shared__ float xs[4][IN_CH];
    // stage 4 x-rows (coalesced)
    for (int i = tid; i < 4 * IN_CH; i += 256) {
        int n = blockIdx.x * 4 + (i >> 7);
        xs[i >> 7][i & 127] = x[(long long)n * IN_CH + (i & 127)];
    }
    __syncthreads();

    const float4* Wr = (const float4*)(W + ch * IN_CH);
    const float4* xr = (const float4*)(xs[local_node]);
    float sum = 0.f;
#pragma unroll 8
    for (int k = 0; k < IN_CH / 4; k++) {
        float4 w4 = Wr[k];
        float4 x4 = xr[k];
        sum += w4.x * x4.x + w4.y * x4.y + w4.z * x4.z + w4.w * x4.w;
    }
    h[(long long)node * OUT_CH + ch] = sum;

    // epilogue: alpha_src/alpha_dst via 16-lane reduction within each head
    const int head = ch >> 4;
    const int k16 = ch & 15;
    float vs = a[head * 32 + k16] * sum;        // a_src part
    float vd = a[head * 32 + 16 + k16] * sum;   // a_dst part
#pragma unroll
    for (int off = 8; off > 0; off >>= 1) {
        vs += __shfl_down(vs, off, 16);
        vd += __shfl_down(vd, off, 16);
    }
    if (k16 == 0) {
        alpha_src[node * HEADS + head] = vs;
        alpha_dst[node * HEADS + head] = vd;
    }
}

// Kernel 2: per-edge attention numerator -> segment-sum denominator
__global__ __launch_bounds__(256) void edge_att_kernel(
    const int* __restrict__ ei,         // [2, N_EDGES] (int32 from harness)
    const float* __restrict__ ew,       // [N_EDGES]
    const float* __restrict__ alpha_src,
    const float* __restrict__ alpha_dst,
    float* __restrict__ att_sum)        // [N_NODES, 4] (pre-zeroed)
{
    int e = blockIdx.x * blockDim.x + threadIdx.x;
    if (e >= N_EDGES) return;
    int s = ei[e];
    int d = ei[N_EDGES + e];
    float w = ew[e];
#pragma unroll
    for (int hd = 0; hd < HEADS; hd++) {
        float att = alpha_src[s * HEADS + hd] + alpha_dst[d * HEADS + hd];
        att = att > 0.f ? att : NEG_SLOPE * att;
        att = expf(att * w);
        atomicAdd(&att_sum[d * HEADS + hd], att);
    }
}

// Kernel 3: out[dst] += h[src] * att_norm  — one wave per edge, lane = channel
__global__ __launch_bounds__(256) void aggregate_kernel(
    const int* __restrict__ ei,
    const float* __restrict__ ew,
    const float* __restrict__ alpha_src,
    const float* __restrict__ alpha_dst,
    const float* __restrict__ att_sum,
    const float* __restrict__ h,
    float* __restrict__ out)            // [N_NODES, 64] (pre-zeroed)
{
    int e = blockIdx.x * 4 + (threadIdx.x >> 6);
    int lane = threadIdx.x & 63;
    if (e >= N_EDGES) return;
    int s = ei[e];
    int d = ei[N_EDGES + e];
    float w = ew[e];
    int hd = lane >> 4;
    float att = alpha_src[s * HEADS + hd] + alpha_dst[d * HEADS + hd];
    att = att > 0.f ? att : NEG_SLOPE * att;
    att = expf(att * w) / (att_sum[d * HEADS + hd] + EPS);
    atomicAdd(&out[(long long)d * OUT_CH + lane],
              h[(long long)s * OUT_CH + lane] * att);
}

extern "C" void kernel_launch(void* const* d_in, const int* in_sizes, int n_in,
                              void* d_out, int out_size, void* d_ws, size_t ws_size,
                              hipStream_t stream) {
    const float* x  = (const float*)d_in[0];
    const int*   ei = (const int*)d_in[1];     // int32 per harness contract
    const float* ew = (const float*)d_in[2];
    const float* W  = (const float*)d_in[3];
    const float* a  = (const float*)d_in[4];
    float* out = (float*)d_out;

    // workspace layout
    char* ws = (char*)d_ws;
    float* h         = (float*)ws;                                   // 25.6 MB
    float* alpha_src = (float*)(ws + (size_t)N_NODES * OUT_CH * 4);  // 1.6 MB
    float* alpha_dst = alpha_src + (size_t)N_NODES * HEADS;          // 1.6 MB
    float* att_sum   = alpha_dst + (size_t)N_NODES * HEADS;          // 1.6 MB

    hipMemsetAsync(att_sum, 0, (size_t)N_NODES * HEADS * sizeof(float), stream);
    hipMemsetAsync(d_out, 0, (size_t)out_size * sizeof(float), stream);

    gemm_alpha_kernel<<<N_NODES / 4, 256, 0, stream>>>(x, W, a, h, alpha_src, alpha_dst);
    edge_att_kernel<<<(N_EDGES + 255) / 256, 256, 0, stream>>>(ei, ew, alpha_src, alpha_dst, att_sum);
    aggregate_kernel<<<N_EDGES / 4, 256, 0, stream>>>(ei, ew, alpha_src, alpha_dst, att_sum, h, out);
}

// Round 3
// 674.494 us; speedup vs baseline: 1.6726x; 1.6726x over previous
//
#include <hip/hip_runtime.h>
#include <math.h>

#define N_NODES 100000
#define N_EDGES 1600000
#define IN_CH 128
#define HEADS 4
#define HEAD_DIM 16
#define OUT_CH 64
#define NEG_SLOPE 0.2f
#define EPS 1e-8f

// ---------------------------------------------------------------------------
// Kernel 1 v2: h = x @ W.T + per-node attention-logit halves.
// Block = 256 threads handles 64 nodes. Lane = output channel; each lane keeps
// its W row (128 floats) in VGPRs (loaded once per block, L1-amortized across
// the 4 waves which all read the same rows). x rows staged coalesced into LDS
// and read back as wave-uniform broadcasts (no bank conflicts).
// ---------------------------------------------------------------------------
__global__ __launch_bounds__(256) void gemm_alpha_kernel(
    const float* __restrict__ x,      // [N_NODES, 128]
    const float* __restrict__ W,      // [64, 128]
    const float* __restrict__ a,      // [1, 4, 32]
    float* __restrict__ h,            // [N_NODES, 64]
    float* __restrict__ alpha_src,    // [N_NODES, 4]
    float* __restrict__ alpha_dst)    // [N_NODES, 4]
{
    const int tid = threadIdx.x;
    const int ch = tid & 63;
    const int wv = tid >> 6;          // wave id 0..3
    const int node0 = blockIdx.x * 64;

    __shared__ float4 xs[64 * 32];    // 64 rows x 128 floats = 32 KB

    // stage 64 x-rows, coalesced float4
    const float4* x4 = (const float4*)x;
    for (int i = tid; i < 64 * 32; i += 256) {
        int node = node0 + (i >> 5);
        xs[i] = (node < N_NODES) ? x4[(long long)node * 32 + (i & 31)]
                                 : make_float4(0.f, 0.f, 0.f, 0.f);
    }

    // W row for this lane -> registers (32 float4 = 128 VGPRs)
    float4 wreg[32];
    const float4* Wr = (const float4*)(W + ch * IN_CH);
#pragma unroll
    for (int k = 0; k < 32; k++) wreg[k] = Wr[k];

    __syncthreads();

    const int head = ch >> 4;
    const int k16 = ch & 15;
    const float a_s = a[head * 32 + k16];
    const float a_d = a[head * 32 + 16 + k16];

    for (int nl = wv; nl < 64; nl += 4) {
        int node = node0 + nl;
        if (node >= N_NODES) break;
        const float4* xr = &xs[nl * 32];
        float4 acc = make_float4(0.f, 0.f, 0.f, 0.f);
#pragma unroll
        for (int k = 0; k < 32; k++) {
            float4 xv = xr[k];        // wave-uniform broadcast ds_read_b128
            acc.x += xv.x * wreg[k].x;
            acc.y += xv.y * wreg[k].y;
            acc.z += xv.z * wreg[k].z;
            acc.w += xv.w * wreg[k].w;
        }
        float sum = (acc.x + acc.y) + (acc.z + acc.w);
        h[(long long)node * OUT_CH + ch] = sum;

        float vs = a_s * sum;
        float vd = a_d * sum;
#pragma unroll
        for (int off = 8; off > 0; off >>= 1) {
            vs += __shfl_down(vs, off, 16);
            vd += __shfl_down(vd, off, 16);
        }
        if (k16 == 0) {
            alpha_src[node * HEADS + head] = vs;
            alpha_dst[node * HEADS + head] = vd;
        }
    }
}

// ---------------------------------------------------------------------------
// CSR build: histogram -> single-block scan -> fill (atomic cursors)
// ---------------------------------------------------------------------------
__global__ __launch_bounds__(256) void hist_kernel(
    const int* __restrict__ ei, int* __restrict__ deg)
{
    int e = blockIdx.x * 256 + threadIdx.x;
    if (e < N_EDGES) atomicAdd(&deg[ei[N_EDGES + e]], 1);
}

__global__ __launch_bounds__(256) void scan_kernel(
    const int* __restrict__ deg, int* __restrict__ ptr, int* __restrict__ cursor)
{
    __shared__ int part[256];
    const int t = threadIdx.x;
    const int CHUNK = (N_NODES + 255) / 256;   // 391
    const int start = t * CHUNK;
    const int end = min(start + CHUNK, N_NODES);

    int s = 0;
    for (int i = start; i < end; i++) s += deg[i];
    part[t] = s;
    __syncthreads();
    // inclusive Hillis-Steele scan over 256 partials
    for (int off = 1; off < 256; off <<= 1) {
        int v = (t >= off) ? part[t - off] : 0;
        __syncthreads();
        part[t] += v;
        __syncthreads();
    }
    int run = part[t] - s;                     // exclusive prefix of this chunk
    for (int i = start; i < end; i++) {
        ptr[i] = run;
        cursor[i] = run;
        run += deg[i];
    }
    if (t == 255) ptr[N_NODES] = run;
}

__global__ __launch_bounds__(256) void fill_kernel(
    const int* __restrict__ ei, const float* __restrict__ ew,
    int* __restrict__ cursor, int2* __restrict__ csr)
{
    int e = blockIdx.x * 256 + threadIdx.x;
    if (e >= N_EDGES) return;
    int s = ei[e];
    int d = ei[N_EDGES + e];
    int idx = atomicAdd(&cursor[d], 1);
    csr[idx] = make_int2(s, __float_as_int(ew[e]));
}

// ---------------------------------------------------------------------------
// Aggregate: one wave per dst node, lane = channel. Cooperative edge-list
// load, per-edge coalesced h-gather, numerator + denominator in one pass
// (normalization is linear), single coalesced store. No atomics.
// ---------------------------------------------------------------------------
__global__ __launch_bounds__(256) void aggregate_kernel(
    const int* __restrict__ ptr,
    const int2* __restrict__ csr,
    const float* __restrict__ alpha_src,
    const float* __restrict__ alpha_dst,
    const float* __restrict__ h,
    float* __restrict__ out)
{
    const int n = blockIdx.x * 4 + (threadIdx.x >> 6);
    const int lane = threadIdx.x & 63;
    if (n >= N_NODES) return;
    const int hd = lane >> 4;

    const int beg = ptr[n];
    const int end = ptr[n + 1];
    const float ad = alpha_dst[n * HEADS + hd];

    float acc = 0.f;
    float denom = 0.f;
    for (int base = beg; base < end; base += 64) {
        int cnt = min(64, end - base);
        int s_l = 0;
        float w_l = 0.f;
        if (lane < cnt) {
            int2 p = csr[base + lane];
            s_l = p.x;
            w_l = __int_as_float(p.y);
        }
        for (int j = 0; j < cnt; j++) {
            int s = __shfl(s_l, j, 64);
            float w = __shfl(w_l, j, 64);
            float att = alpha_src[s * HEADS + hd] + ad;
            att = att > 0.f ? att : NEG_SLOPE * att;
            float e = __expf(att * w);
            denom += e;
            acc += e * h[(long long)s * OUT_CH + lane];
        }
    }
    out[(long long)n * OUT_CH + lane] = acc / (denom + EPS);
}

extern "C" void kernel_launch(void* const* d_in, const int* in_sizes, int n_in,
                              void* d_out, int out_size, void* d_ws, size_t ws_size,
                              hipStream_t stream) {
    const float* x  = (const float*)d_in[0];
    const int*   ei = (const int*)d_in[1];     // int32 per harness contract
    const float* ew = (const float*)d_in[2];
    const float* W  = (const float*)d_in[3];
    const float* a  = (const float*)d_in[4];
    float* out = (float*)d_out;

    // workspace layout (all 16B-aligned)
    char* p = (char*)d_ws;
    float* h         = (float*)p;  p += (size_t)N_NODES * OUT_CH * 4;   // 25.6 MB
    float* alpha_src = (float*)p;  p += (size_t)N_NODES * HEADS * 4;    // 1.6 MB
    float* alpha_dst = (float*)p;  p += (size_t)N_NODES * HEADS * 4;    // 1.6 MB
    int*   deg       = (int*)p;    p += (size_t)N_NODES * 4;            // 0.4 MB
    int*   ptr       = (int*)p;    p += (size_t)(N_NODES + 4) * 4;      // 0.4 MB
    int*   cursor    = (int*)p;    p += (size_t)N_NODES * 4;            // 0.4 MB
    int2*  csr       = (int2*)p;                                        // 12.8 MB

    hipMemsetAsync(deg, 0, (size_t)N_NODES * sizeof(int), stream);

    hist_kernel<<<(N_EDGES + 255) / 256, 256, 0, stream>>>(ei, deg);
    gemm_alpha_kernel<<<(N_NODES + 63) / 64, 256, 0, stream>>>(x, W, a, h, alpha_src, alpha_dst);
    scan_kernel<<<1, 256, 0, stream>>>(deg, ptr, cursor);
    fill_kernel<<<(N_EDGES + 255) / 256, 256, 0, stream>>>(ei, ew, cursor, csr);
    aggregate_kernel<<<(N_NODES + 3) / 4, 256, 0, stream>>>(ptr, csr, alpha_src, alpha_dst, h, out);
}

// Round 4
// 457.961 us; speedup vs baseline: 2.4634x; 1.4728x over previous
//
#include <hip/hip_runtime.h>
#include <math.h>

#define N_NODES 100000
#define N_EDGES 1600000
#define IN_CH 128
#define HEADS 4
#define HEAD_DIM 16
#define OUT_CH 64
#define NEG_SLOPE 0.2f
#define EPS 1e-8f
#define SCAN_BLOCKS ((N_NODES + 255) / 256)   // 391

// ---------------------------------------------------------------------------
// Kernel 1: h = x @ W.T + per-node attention-logit halves.
// Block = 256 threads handles 64 nodes. Lane = output channel; W row lives in
// VGPRs; x rows staged coalesced into LDS, read back as wave-uniform
// broadcasts (conflict-free).
// ---------------------------------------------------------------------------
__global__ __launch_bounds__(256) void gemm_alpha_kernel(
    const float* __restrict__ x,      // [N_NODES, 128]
    const float* __restrict__ W,      // [64, 128]
    const float* __restrict__ a,      // [1, 4, 32]
    float* __restrict__ h,            // [N_NODES, 64]
    float* __restrict__ alpha_src,    // [N_NODES, 4]
    float* __restrict__ alpha_dst)    // [N_NODES, 4]
{
    const int tid = threadIdx.x;
    const int ch = tid & 63;
    const int wv = tid >> 6;
    const int node0 = blockIdx.x * 64;

    __shared__ float4 xs[64 * 32];    // 32 KB

    const float4* x4 = (const float4*)x;
    for (int i = tid; i < 64 * 32; i += 256) {
        int node = node0 + (i >> 5);
        xs[i] = (node < N_NODES) ? x4[(long long)node * 32 + (i & 31)]
                                 : make_float4(0.f, 0.f, 0.f, 0.f);
    }

    float4 wreg[32];
    const float4* Wr = (const float4*)(W + ch * IN_CH);
#pragma unroll
    for (int k = 0; k < 32; k++) wreg[k] = Wr[k];

    __syncthreads();

    const int head = ch >> 4;
    const int k16 = ch & 15;
    const float a_s = a[head * 32 + k16];
    const float a_d = a[head * 32 + 16 + k16];

    for (int nl = wv; nl < 64; nl += 4) {
        int node = node0 + nl;
        if (node >= N_NODES) break;
        const float4* xr = &xs[nl * 32];
        float4 acc = make_float4(0.f, 0.f, 0.f, 0.f);
#pragma unroll
        for (int k = 0; k < 32; k++) {
            float4 xv = xr[k];
            acc.x += xv.x * wreg[k].x;
            acc.y += xv.y * wreg[k].y;
            acc.z += xv.z * wreg[k].z;
            acc.w += xv.w * wreg[k].w;
        }
        float sum = (acc.x + acc.y) + (acc.z + acc.w);
        h[(long long)node * OUT_CH + ch] = sum;

        float vs = a_s * sum;
        float vd = a_d * sum;
#pragma unroll
        for (int off = 8; off > 0; off >>= 1) {
            vs += __shfl_down(vs, off, 16);
            vd += __shfl_down(vd, off, 16);
        }
        if (k16 == 0) {
            alpha_src[node * HEADS + head] = vs;
            alpha_dst[node * HEADS + head] = vd;
        }
    }
}

// ---------------------------------------------------------------------------
// CSR build: histogram -> 3-phase scan -> fill (atomic cursors)
// ---------------------------------------------------------------------------
__global__ __launch_bounds__(256) void hist_kernel(
    const int* __restrict__ ei, int* __restrict__ deg)
{
    int e = blockIdx.x * 256 + threadIdx.x;
    if (e < N_EDGES) atomicAdd(&deg[ei[N_EDGES + e]], 1);
}

__global__ __launch_bounds__(256) void scan_reduce_kernel(
    const int* __restrict__ deg, int* __restrict__ blockSums)
{
    __shared__ int sdata[256];
    int t = threadIdx.x;
    int i = blockIdx.x * 256 + t;
    sdata[t] = (i < N_NODES) ? deg[i] : 0;
    __syncthreads();
    for (int off = 128; off > 0; off >>= 1) {
        if (t < off) sdata[t] += sdata[t + off];
        __syncthreads();
    }
    if (t == 0) blockSums[blockIdx.x] = sdata[0];
}

__global__ __launch_bounds__(512) void scan_blocksums_kernel(
    const int* __restrict__ blockSums, int* __restrict__ blockOffsets,
    int* __restrict__ ptr)
{
    __shared__ int part[512];
    int t = threadIdx.x;
    int v = (t < SCAN_BLOCKS) ? blockSums[t] : 0;
    part[t] = v;
    __syncthreads();
    for (int off = 1; off < 512; off <<= 1) {
        int xv = (t >= off) ? part[t - off] : 0;
        __syncthreads();
        part[t] += xv;
        __syncthreads();
    }
    if (t < SCAN_BLOCKS) blockOffsets[t] = part[t] - v;  // exclusive
    if (t == 0) ptr[N_NODES] = N_EDGES;
}

__global__ __launch_bounds__(256) void scan_final_kernel(
    const int* __restrict__ deg, const int* __restrict__ blockOffsets,
    int* __restrict__ ptr, int* __restrict__ cursor)
{
    __shared__ int part[256];
    int t = threadIdx.x;
    int i = blockIdx.x * 256 + t;
    int v = (i < N_NODES) ? deg[i] : 0;
    part[t] = v;
    __syncthreads();
    for (int off = 1; off < 256; off <<= 1) {
        int xv = (t >= off) ? part[t - off] : 0;
        __syncthreads();
        part[t] += xv;
        __syncthreads();
    }
    if (i < N_NODES) {
        int excl = blockOffsets[blockIdx.x] + part[t] - v;
        ptr[i] = excl;
        cursor[i] = excl;
    }
}

__global__ __launch_bounds__(256) void fill_kernel(
    const int* __restrict__ ei, const float* __restrict__ ew,
    int* __restrict__ cursor, int2* __restrict__ csr)
{
    int e = blockIdx.x * 256 + threadIdx.x;
    if (e >= N_EDGES) return;
    int s = ei[e];
    int d = ei[N_EDGES + e];
    int idx = atomicAdd(&cursor[d], 1);
    csr[idx] = make_int2(s, __float_as_int(ew[e]));
}

// ---------------------------------------------------------------------------
// Aggregate: one wave per dst node, lane = channel. One pass (normalization
// is linear). No atomics.
// ---------------------------------------------------------------------------
__global__ __launch_bounds__(256) void aggregate_kernel(
    const int* __restrict__ ptr,
    const int2* __restrict__ csr,
    const float* __restrict__ alpha_src,
    const float* __restrict__ alpha_dst,
    const float* __restrict__ h,
    float* __restrict__ out)
{
    const int n = blockIdx.x * 4 + (threadIdx.x >> 6);
    const int lane = threadIdx.x & 63;
    if (n >= N_NODES) return;
    const int hd = lane >> 4;

    const int beg = ptr[n];
    const int end = ptr[n + 1];
    const float ad = alpha_dst[n * HEADS + hd];

    float acc = 0.f;
    float denom = 0.f;
    for (int base = beg; base < end; base += 64) {
        int cnt = min(64, end - base);
        int s_l = 0;
        float w_l = 0.f;
        if (lane < cnt) {
            int2 p = csr[base + lane];
            s_l = p.x;
            w_l = __int_as_float(p.y);
        }
        for (int j = 0; j < cnt; j++) {
            int s = __shfl(s_l, j, 64);
            float w = __shfl(w_l, j, 64);
            float att = alpha_src[s * HEADS + hd] + ad;
            att = att > 0.f ? att : NEG_SLOPE * att;
            float e = __expf(att * w);
            denom += e;
            acc += e * h[(long long)s * OUT_CH + lane];
        }
    }
    out[(long long)n * OUT_CH + lane] = acc / (denom + EPS);
}

extern "C" void kernel_launch(void* const* d_in, const int* in_sizes, int n_in,
                              void* d_out, int out_size, void* d_ws, size_t ws_size,
                              hipStream_t stream) {
    const float* x  = (const float*)d_in[0];
    const int*   ei = (const int*)d_in[1];     // int32 per harness contract
    const float* ew = (const float*)d_in[2];
    const float* W  = (const float*)d_in[3];
    const float* a  = (const float*)d_in[4];
    float* out = (float*)d_out;

    // workspace layout (all 16B-aligned)
    char* p = (char*)d_ws;
    float* h         = (float*)p;  p += (size_t)N_NODES * OUT_CH * 4;   // 25.6 MB
    float* alpha_src = (float*)p;  p += (size_t)N_NODES * HEADS * 4;
    float* alpha_dst = (float*)p;  p += (size_t)N_NODES * HEADS * 4;
    int*   deg       = (int*)p;    p += (size_t)N_NODES * 4;
    int*   ptr       = (int*)p;    p += (size_t)(N_NODES + 4) * 4;
    int*   cursor    = (int*)p;    p += (size_t)N_NODES * 4;
    int*   blockSums = (int*)p;    p += (size_t)((SCAN_BLOCKS + 3) & ~3) * 4;
    int*   blockOffs = (int*)p;    p += (size_t)((SCAN_BLOCKS + 3) & ~3) * 4;
    int2*  csr       = (int2*)p;                                        // 12.8 MB

    hipMemsetAsync(deg, 0, (size_t)N_NODES * sizeof(int), stream);

    hist_kernel<<<(N_EDGES + 255) / 256, 256, 0, stream>>>(ei, deg);
    gemm_alpha_kernel<<<(N_NODES + 63) / 64, 256, 0, stream>>>(x, W, a, h, alpha_src, alpha_dst);
    scan_reduce_kernel<<<SCAN_BLOCKS, 256, 0, stream>>>(deg, blockSums);
    scan_blocksums_kernel<<<1, 512, 0, stream>>>(blockSums, blockOffs, ptr);
    scan_final_kernel<<<SCAN_BLOCKS, 256, 0, stream>>>(deg, blockOffs, ptr, cursor);
    fill_kernel<<<(N_EDGES + 255) / 256, 256, 0, stream>>>(ei, ew, cursor, csr);
    aggregate_kernel<<<(N_NODES + 3) / 4, 256, 0, stream>>>(ptr, csr, alpha_src, alpha_dst, h, out);
}

// Round 5
// 394.800 us; speedup vs baseline: 2.8575x; 1.1600x over previous
//
#include <hip/hip_runtime.h>
#include <math.h>

#define N_NODES 100000
#define N_EDGES 1600000
#define IN_CH 128
#define HEADS 4
#define HEAD_DIM 16
#define OUT_CH 64
#define NEG_SLOPE 0.2f
#define EPS 1e-8f
#define SCAN_BLOCKS ((N_NODES + 255) / 256)   // 391

// ---------------------------------------------------------------------------
// Kernel 1: h = x @ W.T + per-node attention-logit halves.
// Block = 256 threads handles 64 nodes. Lane = output channel; W row lives in
// VGPRs; x rows staged coalesced into LDS, read back as wave-uniform
// broadcasts (conflict-free).
// ---------------------------------------------------------------------------
__global__ __launch_bounds__(256) void gemm_alpha_kernel(
    const float* __restrict__ x,      // [N_NODES, 128]
    const float* __restrict__ W,      // [64, 128]
    const float* __restrict__ a,      // [1, 4, 32]
    float* __restrict__ h,            // [N_NODES, 64]
    float* __restrict__ alpha_src,    // [N_NODES, 4]
    float* __restrict__ alpha_dst)    // [N_NODES, 4]
{
    const int tid = threadIdx.x;
    const int ch = tid & 63;
    const int wv = tid >> 6;
    const int node0 = blockIdx.x * 64;

    __shared__ float4 xs[64 * 32];    // 32 KB

    const float4* x4 = (const float4*)x;
    for (int i = tid; i < 64 * 32; i += 256) {
        int node = node0 + (i >> 5);
        xs[i] = (node < N_NODES) ? x4[(long long)node * 32 + (i & 31)]
                                 : make_float4(0.f, 0.f, 0.f, 0.f);
    }

    float4 wreg[32];
    const float4* Wr = (const float4*)(W + ch * IN_CH);
#pragma unroll
    for (int k = 0; k < 32; k++) wreg[k] = Wr[k];

    __syncthreads();

    const int head = ch >> 4;
    const int k16 = ch & 15;
    const float a_s = a[head * 32 + k16];
    const float a_d = a[head * 32 + 16 + k16];

    for (int nl = wv; nl < 64; nl += 4) {
        int node = node0 + nl;
        if (node >= N_NODES) break;
        const float4* xr = &xs[nl * 32];
        float4 acc = make_float4(0.f, 0.f, 0.f, 0.f);
#pragma unroll
        for (int k = 0; k < 32; k++) {
            float4 xv = xr[k];
            acc.x += xv.x * wreg[k].x;
            acc.y += xv.y * wreg[k].y;
            acc.z += xv.z * wreg[k].z;
            acc.w += xv.w * wreg[k].w;
        }
        float sum = (acc.x + acc.y) + (acc.z + acc.w);
        h[(long long)node * OUT_CH + ch] = sum;

        float vs = a_s * sum;
        float vd = a_d * sum;
#pragma unroll
        for (int off = 8; off > 0; off >>= 1) {
            vs += __shfl_down(vs, off, 16);
            vd += __shfl_down(vd, off, 16);
        }
        if (k16 == 0) {
            alpha_src[node * HEADS + head] = vs;
            alpha_dst[node * HEADS + head] = vd;
        }
    }
}

// ---------------------------------------------------------------------------
// CSR build: histogram+rank -> 3-phase scan -> atomic-free fill
// ---------------------------------------------------------------------------
__global__ __launch_bounds__(256) void hist_rank_kernel(
    const int* __restrict__ ei, int* __restrict__ deg, int* __restrict__ rank)
{
    int e = blockIdx.x * 256 + threadIdx.x;
    if (e < N_EDGES) rank[e] = atomicAdd(&deg[ei[N_EDGES + e]], 1);
}

__global__ __launch_bounds__(256) void scan_reduce_kernel(
    const int* __restrict__ deg, int* __restrict__ blockSums)
{
    __shared__ int sdata[256];
    int t = threadIdx.x;
    int i = blockIdx.x * 256 + t;
    sdata[t] = (i < N_NODES) ? deg[i] : 0;
    __syncthreads();
    for (int off = 128; off > 0; off >>= 1) {
        if (t < off) sdata[t] += sdata[t + off];
        __syncthreads();
    }
    if (t == 0) blockSums[blockIdx.x] = sdata[0];
}

__global__ __launch_bounds__(512) void scan_blocksums_kernel(
    const int* __restrict__ blockSums, int* __restrict__ blockOffsets,
    int* __restrict__ ptr)
{
    __shared__ int part[512];
    int t = threadIdx.x;
    int v = (t < SCAN_BLOCKS) ? blockSums[t] : 0;
    part[t] = v;
    __syncthreads();
    for (int off = 1; off < 512; off <<= 1) {
        int xv = (t >= off) ? part[t - off] : 0;
        __syncthreads();
        part[t] += xv;
        __syncthreads();
    }
    if (t < SCAN_BLOCKS) blockOffsets[t] = part[t] - v;  // exclusive
    if (t == 0) ptr[N_NODES] = N_EDGES;
}

__global__ __launch_bounds__(256) void scan_final_kernel(
    const int* __restrict__ deg, const int* __restrict__ blockOffsets,
    int* __restrict__ ptr)
{
    __shared__ int part[256];
    int t = threadIdx.x;
    int i = blockIdx.x * 256 + t;
    int v = (i < N_NODES) ? deg[i] : 0;
    part[t] = v;
    __syncthreads();
    for (int off = 1; off < 256; off <<= 1) {
        int xv = (t >= off) ? part[t - off] : 0;
        __syncthreads();
        part[t] += xv;
        __syncthreads();
    }
    if (i < N_NODES) ptr[i] = blockOffsets[blockIdx.x] + part[t] - v;
}

// Atomic-free fill: idx = ptr[dst] + rank[e]. ptr is 0.4 MB (L2-hot gather);
// ei/ew/rank reads are coalesced; only the int2 store scatters.
__global__ __launch_bounds__(256) void fill_kernel(
    const int* __restrict__ ei, const float* __restrict__ ew,
    const int* __restrict__ rank, const int* __restrict__ ptr,
    int2* __restrict__ csr)
{
    int e = blockIdx.x * 256 + threadIdx.x;
    if (e >= N_EDGES) return;
    int s = ei[e];
    int d = ei[N_EDGES + e];
    int idx = ptr[d] + rank[e];
    csr[idx] = make_int2(s, __float_as_int(ew[e]));
}

// ---------------------------------------------------------------------------
// Aggregate: one wave per dst node, lane = channel. One pass (normalization
// is linear). No atomics.
// ---------------------------------------------------------------------------
__global__ __launch_bounds__(256) void aggregate_kernel(
    const int* __restrict__ ptr,
    const int2* __restrict__ csr,
    const float* __restrict__ alpha_src,
    const float* __restrict__ alpha_dst,
    const float* __restrict__ h,
    float* __restrict__ out)
{
    const int n = blockIdx.x * 4 + (threadIdx.x >> 6);
    const int lane = threadIdx.x & 63;
    if (n >= N_NODES) return;
    const int hd = lane >> 4;

    const int beg = ptr[n];
    const int end = ptr[n + 1];
    const float ad = alpha_dst[n * HEADS + hd];

    float acc = 0.f;
    float denom = 0.f;
    for (int base = beg; base < end; base += 64) {
        int cnt = min(64, end - base);
        int s_l = 0;
        float w_l = 0.f;
        if (lane < cnt) {
            int2 p = csr[base + lane];
            s_l = p.x;
            w_l = __int_as_float(p.y);
        }
        for (int j = 0; j < cnt; j++) {
            int s = __shfl(s_l, j, 64);
            float w = __shfl(w_l, j, 64);
            float att = alpha_src[s * HEADS + hd] + ad;
            att = att > 0.f ? att : NEG_SLOPE * att;
            float e = __expf(att * w);
            denom += e;
            acc += e * h[(long long)s * OUT_CH + lane];
        }
    }
    out[(long long)n * OUT_CH + lane] = acc / (denom + EPS);
}

extern "C" void kernel_launch(void* const* d_in, const int* in_sizes, int n_in,
                              void* d_out, int out_size, void* d_ws, size_t ws_size,
                              hipStream_t stream) {
    const float* x  = (const float*)d_in[0];
    const int*   ei = (const int*)d_in[1];     // int32 per harness contract
    const float* ew = (const float*)d_in[2];
    const float* W  = (const float*)d_in[3];
    const float* a  = (const float*)d_in[4];
    float* out = (float*)d_out;

    // workspace layout (all 16B-aligned)
    char* p = (char*)d_ws;
    float* h         = (float*)p;  p += (size_t)N_NODES * OUT_CH * 4;   // 25.6 MB
    float* alpha_src = (float*)p;  p += (size_t)N_NODES * HEADS * 4;
    float* alpha_dst = (float*)p;  p += (size_t)N_NODES * HEADS * 4;
    int*   deg       = (int*)p;    p += (size_t)N_NODES * 4;
    int*   ptr       = (int*)p;    p += (size_t)(N_NODES + 4) * 4;
    int*   rank      = (int*)p;    p += (size_t)N_EDGES * 4;            // 6.4 MB
    int*   blockSums = (int*)p;    p += (size_t)((SCAN_BLOCKS + 3) & ~3) * 4;
    int*   blockOffs = (int*)p;    p += (size_t)((SCAN_BLOCKS + 3) & ~3) * 4;
    int2*  csr       = (int2*)p;                                        // 12.8 MB

    hipMemsetAsync(deg, 0, (size_t)N_NODES * sizeof(int), stream);

    hist_rank_kernel<<<(N_EDGES + 255) / 256, 256, 0, stream>>>(ei, deg, rank);
    gemm_alpha_kernel<<<(N_NODES + 63) / 64, 256, 0, stream>>>(x, W, a, h, alpha_src, alpha_dst);
    scan_reduce_kernel<<<SCAN_BLOCKS, 256, 0, stream>>>(deg, blockSums);
    scan_blocksums_kernel<<<1, 512, 0, stream>>>(blockSums, blockOffs, ptr);
    scan_final_kernel<<<SCAN_BLOCKS, 256, 0, stream>>>(deg, blockOffs, ptr);
    fill_kernel<<<(N_EDGES + 255) / 256, 256, 0, stream>>>(ei, ew, rank, ptr, csr);
    aggregate_kernel<<<(N_NODES + 3) / 4, 256, 0, stream>>>(ptr, csr, alpha_src, alpha_dst, h, out);
}

// Round 6
// 373.419 us; speedup vs baseline: 3.0211x; 1.0573x over previous
//
#include <hip/hip_runtime.h>
#include <math.h>

#define N_NODES 100000
#define N_EDGES 1600000
#define IN_CH 128
#define HEADS 4
#define HEAD_DIM 16
#define OUT_CH 64
#define NEG_SLOPE 0.2f
#define EPS 1e-8f
#define SCAN_BLOCKS ((N_NODES + 255) / 256)   // 391

// ---------------------------------------------------------------------------
// Kernel 1: h = x @ W.T (stored fp16) + per-node attention-logit halves.
// ---------------------------------------------------------------------------
__global__ __launch_bounds__(256) void gemm_alpha_kernel(
    const float* __restrict__ x,      // [N_NODES, 128]
    const float* __restrict__ W,      // [64, 128]
    const float* __restrict__ a,      // [1, 4, 32]
    _Float16* __restrict__ h,         // [N_NODES, 64] fp16
    float* __restrict__ alpha_src,    // [N_NODES, 4]
    float* __restrict__ alpha_dst)    // [N_NODES, 4]
{
    const int tid = threadIdx.x;
    const int ch = tid & 63;
    const int wv = tid >> 6;
    const int node0 = blockIdx.x * 64;

    __shared__ float4 xs[64 * 32];    // 32 KB

    const float4* x4 = (const float4*)x;
    for (int i = tid; i < 64 * 32; i += 256) {
        int node = node0 + (i >> 5);
        xs[i] = (node < N_NODES) ? x4[(long long)node * 32 + (i & 31)]
                                 : make_float4(0.f, 0.f, 0.f, 0.f);
    }

    float4 wreg[32];
    const float4* Wr = (const float4*)(W + ch * IN_CH);
#pragma unroll
    for (int k = 0; k < 32; k++) wreg[k] = Wr[k];

    __syncthreads();

    const int head = ch >> 4;
    const int k16 = ch & 15;
    const float a_s = a[head * 32 + k16];
    const float a_d = a[head * 32 + 16 + k16];

    for (int nl = wv; nl < 64; nl += 4) {
        int node = node0 + nl;
        if (node >= N_NODES) break;
        const float4* xr = &xs[nl * 32];
        float4 acc = make_float4(0.f, 0.f, 0.f, 0.f);
#pragma unroll
        for (int k = 0; k < 32; k++) {
            float4 xv = xr[k];
            acc.x += xv.x * wreg[k].x;
            acc.y += xv.y * wreg[k].y;
            acc.z += xv.z * wreg[k].z;
            acc.w += xv.w * wreg[k].w;
        }
        float sum = (acc.x + acc.y) + (acc.z + acc.w);
        h[(long long)node * OUT_CH + ch] = (_Float16)sum;

        float vs = a_s * sum;
        float vd = a_d * sum;
#pragma unroll
        for (int off = 8; off > 0; off >>= 1) {
            vs += __shfl_down(vs, off, 16);
            vd += __shfl_down(vd, off, 16);
        }
        if (k16 == 0) {
            alpha_src[node * HEADS + head] = vs;
            alpha_dst[node * HEADS + head] = vd;
        }
    }
}

// ---------------------------------------------------------------------------
// CSR build: histogram+rank -> 3-phase scan -> atomic-free fill
// ---------------------------------------------------------------------------
__global__ __launch_bounds__(256) void hist_rank_kernel(
    const int* __restrict__ ei, int* __restrict__ deg, int* __restrict__ rank)
{
    int e = blockIdx.x * 256 + threadIdx.x;
    if (e < N_EDGES) rank[e] = atomicAdd(&deg[ei[N_EDGES + e]], 1);
}

__global__ __launch_bounds__(256) void scan_reduce_kernel(
    const int* __restrict__ deg, int* __restrict__ blockSums)
{
    __shared__ int sdata[256];
    int t = threadIdx.x;
    int i = blockIdx.x * 256 + t;
    sdata[t] = (i < N_NODES) ? deg[i] : 0;
    __syncthreads();
    for (int off = 128; off > 0; off >>= 1) {
        if (t < off) sdata[t] += sdata[t + off];
        __syncthreads();
    }
    if (t == 0) blockSums[blockIdx.x] = sdata[0];
}

__global__ __launch_bounds__(512) void scan_blocksums_kernel(
    const int* __restrict__ blockSums, int* __restrict__ blockOffsets,
    int* __restrict__ ptr)
{
    __shared__ int part[512];
    int t = threadIdx.x;
    int v = (t < SCAN_BLOCKS) ? blockSums[t] : 0;
    part[t] = v;
    __syncthreads();
    for (int off = 1; off < 512; off <<= 1) {
        int xv = (t >= off) ? part[t - off] : 0;
        __syncthreads();
        part[t] += xv;
        __syncthreads();
    }
    if (t < SCAN_BLOCKS) blockOffsets[t] = part[t] - v;  // exclusive
    if (t == 0) ptr[N_NODES] = N_EDGES;
}

__global__ __launch_bounds__(256) void scan_final_kernel(
    const int* __restrict__ deg, const int* __restrict__ blockOffsets,
    int* __restrict__ ptr)
{
    __shared__ int part[256];
    int t = threadIdx.x;
    int i = blockIdx.x * 256 + t;
    int v = (i < N_NODES) ? deg[i] : 0;
    part[t] = v;
    __syncthreads();
    for (int off = 1; off < 256; off <<= 1) {
        int xv = (t >= off) ? part[t - off] : 0;
        __syncthreads();
        part[t] += xv;
        __syncthreads();
    }
    if (i < N_NODES) ptr[i] = blockOffsets[blockIdx.x] + part[t] - v;
}

__global__ __launch_bounds__(256) void fill_kernel(
    const int* __restrict__ ei, const float* __restrict__ ew,
    const int* __restrict__ rank, const int* __restrict__ ptr,
    int2* __restrict__ csr)
{
    int e = blockIdx.x * 256 + threadIdx.x;
    if (e >= N_EDGES) return;
    int s = ei[e];
    int d = ei[N_EDGES + e];
    int idx = ptr[d] + rank[e];
    csr[idx] = make_int2(s, __float_as_int(ew[e]));
}

// ---------------------------------------------------------------------------
// Aggregate v2: one wave per dst node, lane = channel.
// Phase A (lane-parallel over a 64-edge chunk): lane j computes the 4 head
// exps for edge j (4 exps/edge total, not 64) -> LDS.
// Phase B (serial): 1 shuffle (src) + 1 broadcast LDS read (exp) + fp16 h
// gather + fma, unrolled x2 for load ILP. No atomics.
// ---------------------------------------------------------------------------
__global__ __launch_bounds__(256) void aggregate_kernel(
    const int* __restrict__ ptr,
    const int2* __restrict__ csr,
    const float4* __restrict__ alpha_src4,   // [N_NODES] (4 heads)
    const float4* __restrict__ alpha_dst4,   // [N_NODES]
    const _Float16* __restrict__ h,          // [N_NODES, 64]
    float* __restrict__ out)
{
    __shared__ float se[4][64 * 4];          // per-wave exp staging, 4 KB

    const int wv = threadIdx.x >> 6;
    const int lane = threadIdx.x & 63;
    const int n = blockIdx.x * 4 + wv;
    if (n >= N_NODES) return;
    const int hd = lane >> 4;

    const int beg = ptr[n];
    const int end = ptr[n + 1];
    const float4 ad4 = alpha_dst4[n];

    float acc0 = 0.f, acc1 = 0.f;
    float denom = 0.f;
    float* se_w = se[wv];

    for (int base = beg; base < end; base += 64) {
        int cnt = min(64, end - base);
        int s_l = 0;
        float4 e4 = make_float4(0.f, 0.f, 0.f, 0.f);
        if (lane < cnt) {
            int2 pr = csr[base + lane];
            s_l = pr.x;
            float w = __int_as_float(pr.y);
            float4 as = alpha_src4[s_l];
            float t0 = as.x + ad4.x; t0 = (t0 > 0.f ? t0 : NEG_SLOPE * t0) * w;
            float t1 = as.y + ad4.y; t1 = (t1 > 0.f ? t1 : NEG_SLOPE * t1) * w;
            float t2 = as.z + ad4.z; t2 = (t2 > 0.f ? t2 : NEG_SLOPE * t2) * w;
            float t3 = as.w + ad4.w; t3 = (t3 > 0.f ? t3 : NEG_SLOPE * t3) * w;
            e4 = make_float4(__expf(t0), __expf(t1), __expf(t2), __expf(t3));
        }
        ((float4*)se_w)[lane] = e4;   // intra-wave; compiler orders DS ops

        int j = 0;
        for (; j + 1 < cnt; j += 2) {
            int s0 = __shfl(s_l, j, 64);
            int s1 = __shfl(s_l, j + 1, 64);
            float ev0 = se_w[j * 4 + hd];
            float ev1 = se_w[(j + 1) * 4 + hd];
            float h0 = (float)h[s0 * OUT_CH + lane];
            float h1 = (float)h[s1 * OUT_CH + lane];
            denom += ev0 + ev1;
            acc0 += ev0 * h0;
            acc1 += ev1 * h1;
        }
        if (j < cnt) {
            int s0 = __shfl(s_l, j, 64);
            float ev0 = se_w[j * 4 + hd];
            denom += ev0;
            acc0 += ev0 * (float)h[s0 * OUT_CH + lane];
        }
    }
    out[(long long)n * OUT_CH + lane] = (acc0 + acc1) / (denom + EPS);
}

extern "C" void kernel_launch(void* const* d_in, const int* in_sizes, int n_in,
                              void* d_out, int out_size, void* d_ws, size_t ws_size,
                              hipStream_t stream) {
    const float* x  = (const float*)d_in[0];
    const int*   ei = (const int*)d_in[1];     // int32 per harness contract
    const float* ew = (const float*)d_in[2];
    const float* W  = (const float*)d_in[3];
    const float* a  = (const float*)d_in[4];
    float* out = (float*)d_out;

    // workspace layout (all 16B-aligned)
    char* p = (char*)d_ws;
    _Float16* h      = (_Float16*)p; p += (size_t)N_NODES * OUT_CH * 2;  // 12.8 MB
    float* alpha_src = (float*)p;  p += (size_t)N_NODES * HEADS * 4;     // 1.6 MB
    float* alpha_dst = (float*)p;  p += (size_t)N_NODES * HEADS * 4;     // 1.6 MB
    int*   deg       = (int*)p;    p += (size_t)N_NODES * 4;
    int*   ptr       = (int*)p;    p += (size_t)(N_NODES + 4) * 4;
    int*   rank      = (int*)p;    p += (size_t)N_EDGES * 4;             // 6.4 MB
    int*   blockSums = (int*)p;    p += (size_t)((SCAN_BLOCKS + 3) & ~3) * 4;
    int*   blockOffs = (int*)p;    p += (size_t)((SCAN_BLOCKS + 3) & ~3) * 4;
    int2*  csr       = (int2*)p;                                         // 12.8 MB

    hipMemsetAsync(deg, 0, (size_t)N_NODES * sizeof(int), stream);

    hist_rank_kernel<<<(N_EDGES + 255) / 256, 256, 0, stream>>>(ei, deg, rank);
    gemm_alpha_kernel<<<(N_NODES + 63) / 64, 256, 0, stream>>>(x, W, a, h, alpha_src, alpha_dst);
    scan_reduce_kernel<<<SCAN_BLOCKS, 256, 0, stream>>>(deg, blockSums);
    scan_blocksums_kernel<<<1, 512, 0, stream>>>(blockSums, blockOffs, ptr);
    scan_final_kernel<<<SCAN_BLOCKS, 256, 0, stream>>>(deg, blockOffs, ptr);
    fill_kernel<<<(N_EDGES + 255) / 256, 256, 0, stream>>>(ei, ew, rank, ptr, csr);
    aggregate_kernel<<<(N_NODES + 3) / 4, 256, 0, stream>>>(
        ptr, csr, (const float4*)alpha_src, (const float4*)alpha_dst, h, out);
}

// Round 7
// 305.501 us; speedup vs baseline: 3.6928x; 1.2223x over previous
//
#include <hip/hip_runtime.h>
#include <math.h>

#define N_NODES 100000
#define N_EDGES 1600000
#define IN_CH 128
#define HEADS 4
#define HEAD_DIM 16
#define OUT_CH 64
#define NEG_SLOPE 0.2f
#define EPS 1e-8f
#define SCAN_BLOCKS ((N_NODES + 255) / 256)   // 391

typedef _Float16 f16x8 __attribute__((ext_vector_type(8)));
typedef float    f32x4 __attribute__((ext_vector_type(4)));

// ---------------------------------------------------------------------------
// Prep: wsd[8][128] fp32 — w_s rows 0-3, w_d rows 4-7.
// alpha_src[n][hd] = sum_k x[n][k]*wsd[hd][k];  alpha_dst uses rows 4-7.
// ---------------------------------------------------------------------------
__global__ __launch_bounds__(128) void wsd_kernel(
    const float* __restrict__ W, const float* __restrict__ a,
    float* __restrict__ wsd)
{
    int k = threadIdx.x;   // 0..127
#pragma unroll
    for (int hd = 0; hd < 4; hd++) {
        float ss = 0.f, dd = 0.f;
#pragma unroll
        for (int c = 0; c < 16; c++) {
            float wv = W[(hd * 16 + c) * IN_CH + k];
            ss += a[hd * 32 + c] * wv;
            dd += a[hd * 32 + 16 + c] * wv;
        }
        wsd[hd * IN_CH + k] = ss;
        wsd[(4 + hd) * IN_CH + k] = dd;
    }
}

__device__ inline f16x8 cvt8(const float* p) {
    float4 lo = ((const float4*)p)[0];
    float4 hi = ((const float4*)p)[1];
    f16x8 f;
    f[0] = (_Float16)lo.x; f[1] = (_Float16)lo.y;
    f[2] = (_Float16)lo.z; f[3] = (_Float16)lo.w;
    f[4] = (_Float16)hi.x; f[5] = (_Float16)hi.y;
    f[6] = (_Float16)hi.z; f[7] = (_Float16)hi.w;
    return f;
}

// ---------------------------------------------------------------------------
// GEMM via MFMA 16x16x32 f16. Block = 4 waves x 32 nodes = 128 nodes.
// N-tiles 0-3: h channels 0-63 (B = W rows). N-tile 4: alpha (B = wsd rows,
// cols 0-3 = alpha_src heads, 4-7 = alpha_dst heads, 8-15 zero).
// A-frag layout: A[m=lane&15][k=quad*8+j]; C: row=quad*4+reg, col=lane&15.
// ---------------------------------------------------------------------------
__global__ __launch_bounds__(256) void gemm_alpha_kernel(
    const float* __restrict__ x,      // [N_NODES, 128]
    const float* __restrict__ W,      // [64, 128]
    const float* __restrict__ wsd,    // [8, 128]
    _Float16* __restrict__ h,         // [N_NODES, 64] fp16
    float* __restrict__ alpha_src,    // [N_NODES, 4]
    float* __restrict__ alpha_dst)    // [N_NODES, 4]
{
    const int wv = threadIdx.x >> 6;
    const int lane = threadIdx.x & 63;
    const int col = lane & 15;
    const int quad = lane >> 4;
    const int node_base = blockIdx.x * 128 + wv * 32;

    // B-frags: loaded once per wave, reused for both M-tiles.
    f16x8 bfrag[5][4];
#pragma unroll
    for (int nt = 0; nt < 4; nt++) {
        const float* src = W + (nt * 16 + col) * IN_CH;
#pragma unroll
        for (int ks = 0; ks < 4; ks++)
            bfrag[nt][ks] = cvt8(src + ks * 32 + quad * 8);
    }
    {
        const float* src = wsd + (col < 8 ? col : 0) * IN_CH;
#pragma unroll
        for (int ks = 0; ks < 4; ks++) {
            f16x8 f = cvt8(src + ks * 32 + quad * 8);
            if (col >= 8) {
                f16x8 z = {};
                f = z;
            }
            bfrag[4][ks] = f;
        }
    }

#pragma unroll
    for (int mt = 0; mt < 2; mt++) {
        int row_node = node_base + mt * 16 + col;
        int rn = row_node < N_NODES ? row_node : N_NODES - 1;  // clamp (stores masked)
        const float* xrow = x + (long long)rn * IN_CH;

        f16x8 afrag[4];
#pragma unroll
        for (int ks = 0; ks < 4; ks++)
            afrag[ks] = cvt8(xrow + ks * 32 + quad * 8);

        f32x4 acc[5];
#pragma unroll
        for (int nt = 0; nt < 5; nt++) {
            f32x4 z = {0.f, 0.f, 0.f, 0.f};
            acc[nt] = z;
        }
#pragma unroll
        for (int ks = 0; ks < 4; ks++)
#pragma unroll
            for (int nt = 0; nt < 5; nt++)
                acc[nt] = __builtin_amdgcn_mfma_f32_16x16x32_f16(
                    afrag[ks], bfrag[nt][ks], acc[nt], 0, 0, 0);

        // epilogue: h (tiles 0-3) + alpha (tile 4)
#pragma unroll
        for (int r = 0; r < 4; r++) {
            int node = node_base + mt * 16 + quad * 4 + r;
            if (node < N_NODES) {
#pragma unroll
                for (int nt = 0; nt < 4; nt++)
                    h[(long long)node * OUT_CH + nt * 16 + col] = (_Float16)acc[nt][r];
                if (col < 4)      alpha_src[node * HEADS + col]     = acc[4][r];
                else if (col < 8) alpha_dst[node * HEADS + col - 4] = acc[4][r];
            }
        }
    }
}

// ---------------------------------------------------------------------------
// CSR build: histogram+rank -> 3-phase scan -> atomic-free fill
// ---------------------------------------------------------------------------
__global__ __launch_bounds__(256) void hist_rank_kernel(
    const int* __restrict__ ei, int* __restrict__ deg, int* __restrict__ rank)
{
    int e = blockIdx.x * 256 + threadIdx.x;
    if (e < N_EDGES) rank[e] = atomicAdd(&deg[ei[N_EDGES + e]], 1);
}

__global__ __launch_bounds__(256) void scan_reduce_kernel(
    const int* __restrict__ deg, int* __restrict__ blockSums)
{
    __shared__ int sdata[256];
    int t = threadIdx.x;
    int i = blockIdx.x * 256 + t;
    sdata[t] = (i < N_NODES) ? deg[i] : 0;
    __syncthreads();
    for (int off = 128; off > 0; off >>= 1) {
        if (t < off) sdata[t] += sdata[t + off];
        __syncthreads();
    }
    if (t == 0) blockSums[blockIdx.x] = sdata[0];
}

__global__ __launch_bounds__(512) void scan_blocksums_kernel(
    const int* __restrict__ blockSums, int* __restrict__ blockOffsets,
    int* __restrict__ ptr)
{
    __shared__ int part[512];
    int t = threadIdx.x;
    int v = (t < SCAN_BLOCKS) ? blockSums[t] : 0;
    part[t] = v;
    __syncthreads();
    for (int off = 1; off < 512; off <<= 1) {
        int xv = (t >= off) ? part[t - off] : 0;
        __syncthreads();
        part[t] += xv;
        __syncthreads();
    }
    if (t < SCAN_BLOCKS) blockOffsets[t] = part[t] - v;  // exclusive
    if (t == 0) ptr[N_NODES] = N_EDGES;
}

__global__ __launch_bounds__(256) void scan_final_kernel(
    const int* __restrict__ deg, const int* __restrict__ blockOffsets,
    int* __restrict__ ptr)
{
    __shared__ int part[256];
    int t = threadIdx.x;
    int i = blockIdx.x * 256 + t;
    int v = (i < N_NODES) ? deg[i] : 0;
    part[t] = v;
    __syncthreads();
    for (int off = 1; off < 256; off <<= 1) {
        int xv = (t >= off) ? part[t - off] : 0;
        __syncthreads();
        part[t] += xv;
        __syncthreads();
    }
    if (i < N_NODES) ptr[i] = blockOffsets[blockIdx.x] + part[t] - v;
}

__global__ __launch_bounds__(256) void fill_kernel(
    const int* __restrict__ ei, const float* __restrict__ ew,
    const int* __restrict__ rank, const int* __restrict__ ptr,
    int2* __restrict__ csr)
{
    int e = blockIdx.x * 256 + threadIdx.x;
    if (e >= N_EDGES) return;
    int s = ei[e];
    int d = ei[N_EDGES + e];
    int idx = ptr[d] + rank[e];
    csr[idx] = make_int2(s, __float_as_int(ew[e]));
}

// ---------------------------------------------------------------------------
// Aggregate: one wave per dst node, lane = channel.
// Phase A (lane-parallel): lane j computes the 4 head exps for edge j -> LDS.
// Phase B (serial): shuffle src + broadcast LDS exp + fp16 h gather + fma.
// ---------------------------------------------------------------------------
__global__ __launch_bounds__(256) void aggregate_kernel(
    const int* __restrict__ ptr,
    const int2* __restrict__ csr,
    const float4* __restrict__ alpha_src4,   // [N_NODES] (4 heads)
    const float4* __restrict__ alpha_dst4,   // [N_NODES]
    const _Float16* __restrict__ h,          // [N_NODES, 64]
    float* __restrict__ out)
{
    __shared__ float se[4][64 * 4];

    const int wv = threadIdx.x >> 6;
    const int lane = threadIdx.x & 63;
    const int n = blockIdx.x * 4 + wv;
    if (n >= N_NODES) return;
    const int hd = lane >> 4;

    const int beg = ptr[n];
    const int end = ptr[n + 1];
    const float4 ad4 = alpha_dst4[n];

    float acc0 = 0.f, acc1 = 0.f;
    float denom = 0.f;
    float* se_w = se[wv];

    for (int base = beg; base < end; base += 64) {
        int cnt = min(64, end - base);
        int s_l = 0;
        float4 e4 = make_float4(0.f, 0.f, 0.f, 0.f);
        if (lane < cnt) {
            int2 pr = csr[base + lane];
            s_l = pr.x;
            float w = __int_as_float(pr.y);
            float4 as = alpha_src4[s_l];
            float t0 = as.x + ad4.x; t0 = (t0 > 0.f ? t0 : NEG_SLOPE * t0) * w;
            float t1 = as.y + ad4.y; t1 = (t1 > 0.f ? t1 : NEG_SLOPE * t1) * w;
            float t2 = as.z + ad4.z; t2 = (t2 > 0.f ? t2 : NEG_SLOPE * t2) * w;
            float t3 = as.w + ad4.w; t3 = (t3 > 0.f ? t3 : NEG_SLOPE * t3) * w;
            e4 = make_float4(__expf(t0), __expf(t1), __expf(t2), __expf(t3));
        }
        ((float4*)se_w)[lane] = e4;

        int j = 0;
        for (; j + 1 < cnt; j += 2) {
            int s0 = __shfl(s_l, j, 64);
            int s1 = __shfl(s_l, j + 1, 64);
            float ev0 = se_w[j * 4 + hd];
            float ev1 = se_w[(j + 1) * 4 + hd];
            float h0 = (float)h[s0 * OUT_CH + lane];
            float h1 = (float)h[s1 * OUT_CH + lane];
            denom += ev0 + ev1;
            acc0 += ev0 * h0;
            acc1 += ev1 * h1;
        }
        if (j < cnt) {
            int s0 = __shfl(s_l, j, 64);
            float ev0 = se_w[j * 4 + hd];
            denom += ev0;
            acc0 += ev0 * (float)h[s0 * OUT_CH + lane];
        }
    }
    out[(long long)n * OUT_CH + lane] = (acc0 + acc1) / (denom + EPS);
}

extern "C" void kernel_launch(void* const* d_in, const int* in_sizes, int n_in,
                              void* d_out, int out_size, void* d_ws, size_t ws_size,
                              hipStream_t stream) {
    const float* x  = (const float*)d_in[0];
    const int*   ei = (const int*)d_in[1];     // int32 per harness contract
    const float* ew = (const float*)d_in[2];
    const float* W  = (const float*)d_in[3];
    const float* a  = (const float*)d_in[4];
    float* out = (float*)d_out;

    // workspace layout (all 16B-aligned)
    char* p = (char*)d_ws;
    _Float16* h      = (_Float16*)p; p += (size_t)N_NODES * OUT_CH * 2;  // 12.8 MB
    float* alpha_src = (float*)p;  p += (size_t)N_NODES * HEADS * 4;     // 1.6 MB
    float* alpha_dst = (float*)p;  p += (size_t)N_NODES * HEADS * 4;     // 1.6 MB
    float* wsd       = (float*)p;  p += (size_t)8 * IN_CH * 4;           // 4 KB
    int*   deg       = (int*)p;    p += (size_t)N_NODES * 4;
    int*   ptr       = (int*)p;    p += (size_t)(N_NODES + 4) * 4;
    int*   rank      = (int*)p;    p += (size_t)N_EDGES * 4;             // 6.4 MB
    int*   blockSums = (int*)p;    p += (size_t)((SCAN_BLOCKS + 3) & ~3) * 4;
    int*   blockOffs = (int*)p;    p += (size_t)((SCAN_BLOCKS + 3) & ~3) * 4;
    int2*  csr       = (int2*)p;                                         // 12.8 MB

    hipMemsetAsync(deg, 0, (size_t)N_NODES * sizeof(int), stream);

    wsd_kernel<<<1, 128, 0, stream>>>(W, a, wsd);
    hist_rank_kernel<<<(N_EDGES + 255) / 256, 256, 0, stream>>>(ei, deg, rank);
    gemm_alpha_kernel<<<(N_NODES + 127) / 128, 256, 0, stream>>>(x, W, wsd, h, alpha_src, alpha_dst);
    scan_reduce_kernel<<<SCAN_BLOCKS, 256, 0, stream>>>(deg, blockSums);
    scan_blocksums_kernel<<<1, 512, 0, stream>>>(blockSums, blockOffs, ptr);
    scan_final_kernel<<<SCAN_BLOCKS, 256, 0, stream>>>(deg, blockOffs, ptr);
    fill_kernel<<<(N_EDGES + 255) / 256, 256, 0, stream>>>(ei, ew, rank, ptr, csr);
    aggregate_kernel<<<(N_NODES + 3) / 4, 256, 0, stream>>>(
        ptr, csr, (const float4*)alpha_src, (const float4*)alpha_dst, h, out);
}

// Round 8
// 302.880 us; speedup vs baseline: 3.7247x; 1.0087x over previous
//
#include <hip/hip_runtime.h>
#include <math.h>

#define N_NODES 100000
#define N_EDGES 1600000
#define IN_CH 128
#define HEADS 4
#define HEAD_DIM 16
#define OUT_CH 64
#define NEG_SLOPE 0.2f
#define EPS 1e-8f
#define SCAN_BLOCKS ((N_NODES + 255) / 256)   // 391

typedef _Float16 f16x8 __attribute__((ext_vector_type(8)));
typedef _Float16 f16x4 __attribute__((ext_vector_type(4)));
typedef float    f32x4 __attribute__((ext_vector_type(4)));

// ---------------------------------------------------------------------------
// Prep: wsd[8][128] fp32 — w_s rows 0-3, w_d rows 4-7.
// ---------------------------------------------------------------------------
__global__ __launch_bounds__(128) void wsd_kernel(
    const float* __restrict__ W, const float* __restrict__ a,
    float* __restrict__ wsd)
{
    int k = threadIdx.x;   // 0..127
#pragma unroll
    for (int hd = 0; hd < 4; hd++) {
        float ss = 0.f, dd = 0.f;
#pragma unroll
        for (int c = 0; c < 16; c++) {
            float wv = W[(hd * 16 + c) * IN_CH + k];
            ss += a[hd * 32 + c] * wv;
            dd += a[hd * 32 + 16 + c] * wv;
        }
        wsd[hd * IN_CH + k] = ss;
        wsd[(4 + hd) * IN_CH + k] = dd;
    }
}

__device__ inline f16x8 cvt8(const float* p) {
    float4 lo = ((const float4*)p)[0];
    float4 hi = ((const float4*)p)[1];
    f16x8 f;
    f[0] = (_Float16)lo.x; f[1] = (_Float16)lo.y;
    f[2] = (_Float16)lo.z; f[3] = (_Float16)lo.w;
    f[4] = (_Float16)hi.x; f[5] = (_Float16)hi.y;
    f[6] = (_Float16)hi.z; f[7] = (_Float16)hi.w;
    return f;
}

// ---------------------------------------------------------------------------
// GEMM via MFMA 16x16x32 f16. Block = 4 waves x 32 nodes = 128 nodes.
// N-tile 4 carries alpha (wsd rows; cols 0-3 = a_src heads, 4-7 = a_dst).
// ---------------------------------------------------------------------------
__global__ __launch_bounds__(256) void gemm_alpha_kernel(
    const float* __restrict__ x,      // [N_NODES, 128]
    const float* __restrict__ W,      // [64, 128]
    const float* __restrict__ wsd,    // [8, 128]
    _Float16* __restrict__ h,         // [N_NODES, 64] fp16
    float* __restrict__ alpha_src,    // [N_NODES, 4]
    float* __restrict__ alpha_dst)    // [N_NODES, 4]
{
    const int wv = threadIdx.x >> 6;
    const int lane = threadIdx.x & 63;
    const int col = lane & 15;
    const int quad = lane >> 4;
    const int node_base = blockIdx.x * 128 + wv * 32;

    f16x8 bfrag[5][4];
#pragma unroll
    for (int nt = 0; nt < 4; nt++) {
        const float* src = W + (nt * 16 + col) * IN_CH;
#pragma unroll
        for (int ks = 0; ks < 4; ks++)
            bfrag[nt][ks] = cvt8(src + ks * 32 + quad * 8);
    }
    {
        const float* src = wsd + (col < 8 ? col : 0) * IN_CH;
#pragma unroll
        for (int ks = 0; ks < 4; ks++) {
            f16x8 f = cvt8(src + ks * 32 + quad * 8);
            if (col >= 8) {
                f16x8 z = {};
                f = z;
            }
            bfrag[4][ks] = f;
        }
    }

#pragma unroll
    for (int mt = 0; mt < 2; mt++) {
        int row_node = node_base + mt * 16 + col;
        int rn = row_node < N_NODES ? row_node : N_NODES - 1;
        const float* xrow = x + (long long)rn * IN_CH;

        f16x8 afrag[4];
#pragma unroll
        for (int ks = 0; ks < 4; ks++)
            afrag[ks] = cvt8(xrow + ks * 32 + quad * 8);

        f32x4 acc[5];
#pragma unroll
        for (int nt = 0; nt < 5; nt++) {
            f32x4 z = {0.f, 0.f, 0.f, 0.f};
            acc[nt] = z;
        }
#pragma unroll
        for (int ks = 0; ks < 4; ks++)
#pragma unroll
            for (int nt = 0; nt < 5; nt++)
                acc[nt] = __builtin_amdgcn_mfma_f32_16x16x32_f16(
                    afrag[ks], bfrag[nt][ks], acc[nt], 0, 0, 0);

#pragma unroll
        for (int r = 0; r < 4; r++) {
            int node = node_base + mt * 16 + quad * 4 + r;
            if (node < N_NODES) {
#pragma unroll
                for (int nt = 0; nt < 4; nt++)
                    h[(long long)node * OUT_CH + nt * 16 + col] = (_Float16)acc[nt][r];
                if (col < 4)      alpha_src[node * HEADS + col]     = acc[4][r];
                else if (col < 8) alpha_dst[node * HEADS + col - 4] = acc[4][r];
            }
        }
    }
}

// ---------------------------------------------------------------------------
// CSR build: histogram+rank -> 3-phase scan -> atomic-free fill (nt store)
// ---------------------------------------------------------------------------
__global__ __launch_bounds__(256) void hist_rank_kernel(
    const int* __restrict__ ei, int* __restrict__ deg, int* __restrict__ rank)
{
    int e = blockIdx.x * 256 + threadIdx.x;
    if (e < N_EDGES) rank[e] = atomicAdd(&deg[ei[N_EDGES + e]], 1);
}

__global__ __launch_bounds__(256) void scan_reduce_kernel(
    const int* __restrict__ deg, int* __restrict__ blockSums)
{
    __shared__ int sdata[256];
    int t = threadIdx.x;
    int i = blockIdx.x * 256 + t;
    sdata[t] = (i < N_NODES) ? deg[i] : 0;
    __syncthreads();
    for (int off = 128; off > 0; off >>= 1) {
        if (t < off) sdata[t] += sdata[t + off];
        __syncthreads();
    }
    if (t == 0) blockSums[blockIdx.x] = sdata[0];
}

__global__ __launch_bounds__(512) void scan_blocksums_kernel(
    const int* __restrict__ blockSums, int* __restrict__ blockOffsets,
    int* __restrict__ ptr)
{
    __shared__ int part[512];
    int t = threadIdx.x;
    int v = (t < SCAN_BLOCKS) ? blockSums[t] : 0;
    part[t] = v;
    __syncthreads();
    for (int off = 1; off < 512; off <<= 1) {
        int xv = (t >= off) ? part[t - off] : 0;
        __syncthreads();
        part[t] += xv;
        __syncthreads();
    }
    if (t < SCAN_BLOCKS) blockOffsets[t] = part[t] - v;  // exclusive
    if (t == 0) ptr[N_NODES] = N_EDGES;
}

__global__ __launch_bounds__(256) void scan_final_kernel(
    const int* __restrict__ deg, const int* __restrict__ blockOffsets,
    int* __restrict__ ptr)
{
    __shared__ int part[256];
    int t = threadIdx.x;
    int i = blockIdx.x * 256 + t;
    int v = (i < N_NODES) ? deg[i] : 0;
    part[t] = v;
    __syncthreads();
    for (int off = 1; off < 256; off <<= 1) {
        int xv = (t >= off) ? part[t - off] : 0;
        __syncthreads();
        part[t] += xv;
        __syncthreads();
    }
    if (i < N_NODES) ptr[i] = blockOffsets[blockIdx.x] + part[t] - v;
}

__global__ __launch_bounds__(256) void fill_kernel(
    const int* __restrict__ ei, const float* __restrict__ ew,
    const int* __restrict__ rank, const int* __restrict__ ptr,
    long long* __restrict__ csr)
{
    int e = blockIdx.x * 256 + threadIdx.x;
    if (e >= N_EDGES) return;
    int s = ei[e];
    int d = ei[N_EDGES + e];
    int idx = ptr[d] + rank[e];
    long long v = (long long)((unsigned long long)__float_as_uint(ew[e]) << 32)
                | (unsigned int)s;
    __builtin_nontemporal_store(v, &csr[idx]);   // skip write-allocate on scatter
}

// ---------------------------------------------------------------------------
// Aggregate v3: one wave per dst node, quarter-wave edge parallelism.
// Chunk (<=64 edges): lane j loads csr[j], gathers alpha_src, computes 4 head
// exps -> per-wave LDS (src + ev4). Then serial loop: 4 edges/iteration
// (quarter q handles edge 4j+q; lane covers channels 4*(lane&15)..+3 via one
// 8-B f16x4 load). Groups beyond cnt auto-contribute zero (LDS pre-zeroed per
// chunk). Final xor-butterfly over quarters; lanes 0-15 store float4.
// ---------------------------------------------------------------------------
__global__ __launch_bounds__(256) void aggregate_kernel(
    const int* __restrict__ ptr,
    const int2* __restrict__ csr,
    const float4* __restrict__ alpha_src4,   // [N_NODES]
    const float4* __restrict__ alpha_dst4,   // [N_NODES]
    const _Float16* __restrict__ h,          // [N_NODES, 64]
    float* __restrict__ out)
{
    __shared__ float4 sev[4][64];   // per-wave ev4 staging
    __shared__ int    ssc[4][64];   // per-wave src staging

    const int wv = threadIdx.x >> 6;
    const int lane = threadIdx.x & 63;
    const int n = blockIdx.x * 4 + wv;
    if (n >= N_NODES) return;
    const int q = lane >> 4;          // quarter 0..3
    const int cg = lane & 15;         // channel group: ch 4*cg..4*cg+3
    const int hsel = cg >> 2;         // head of this channel group

    const int beg = ptr[n];
    const int end = ptr[n + 1];
    const float4 ad4 = alpha_dst4[n];

    float4 acc = make_float4(0.f, 0.f, 0.f, 0.f);
    float denom = 0.f;
    float4* sev_w = sev[wv];
    int* ssc_w = ssc[wv];

    for (int base = beg; base < end; base += 64) {
        int cnt = min(64, end - base);
        int s_l = 0;
        float4 e4 = make_float4(0.f, 0.f, 0.f, 0.f);
        if (lane < cnt) {
            int2 pr = csr[base + lane];
            s_l = pr.x;
            float w = __int_as_float(pr.y);
            float4 as = alpha_src4[s_l];
            float t0 = as.x + ad4.x; t0 = (t0 > 0.f ? t0 : NEG_SLOPE * t0) * w;
            float t1 = as.y + ad4.y; t1 = (t1 > 0.f ? t1 : NEG_SLOPE * t1) * w;
            float t2 = as.z + ad4.z; t2 = (t2 > 0.f ? t2 : NEG_SLOPE * t2) * w;
            float t3 = as.w + ad4.w; t3 = (t3 > 0.f ? t3 : NEG_SLOPE * t3) * w;
            e4 = make_float4(__expf(t0), __expf(t1), __expf(t2), __expf(t3));
        }
        sev_w[lane] = e4;         // intra-wave LDS, no barrier needed
        ssc_w[lane] = s_l;

        int iters = (cnt + 3) >> 2;
        for (int j0 = 0; j0 < iters; j0 += 2) {
            int idx0 = j0 * 4 + q;
            int idx1 = idx0 + 4;          // may pass cnt: contributes zero
            int s0 = ssc_w[idx0];
            int s1 = ssc_w[idx1];
            float ev0 = ((const float*)&sev_w[idx0])[hsel];
            float ev1 = ((const float*)&sev_w[idx1])[hsel];
            f16x4 h0 = *(const f16x4*)(h + s0 * OUT_CH + cg * 4);
            f16x4 h1 = *(const f16x4*)(h + s1 * OUT_CH + cg * 4);
            acc.x += ev0 * (float)h0[0] + ev1 * (float)h1[0];
            acc.y += ev0 * (float)h0[1] + ev1 * (float)h1[1];
            acc.z += ev0 * (float)h0[2] + ev1 * (float)h1[2];
            acc.w += ev0 * (float)h0[3] + ev1 * (float)h1[3];
            denom += ev0 + ev1;
        }
    }

    // combine the 4 quarters (xor butterfly) — every lane ends with totals
    denom += __shfl_xor(denom, 16);
    denom += __shfl_xor(denom, 32);
    acc.x += __shfl_xor(acc.x, 16);  acc.x += __shfl_xor(acc.x, 32);
    acc.y += __shfl_xor(acc.y, 16);  acc.y += __shfl_xor(acc.y, 32);
    acc.z += __shfl_xor(acc.z, 16);  acc.z += __shfl_xor(acc.z, 32);
    acc.w += __shfl_xor(acc.w, 16);  acc.w += __shfl_xor(acc.w, 32);

    if (lane < 16) {
        float inv = 1.f / (denom + EPS);
        float4 r = make_float4(acc.x * inv, acc.y * inv, acc.z * inv, acc.w * inv);
        ((float4*)(out + (long long)n * OUT_CH))[cg] = r;
    }
}

extern "C" void kernel_launch(void* const* d_in, const int* in_sizes, int n_in,
                              void* d_out, int out_size, void* d_ws, size_t ws_size,
                              hipStream_t stream) {
    const float* x  = (const float*)d_in[0];
    const int*   ei = (const int*)d_in[1];     // int32 per harness contract
    const float* ew = (const float*)d_in[2];
    const float* W  = (const float*)d_in[3];
    const float* a  = (const float*)d_in[4];
    float* out = (float*)d_out;

    // workspace layout (all 16B-aligned)
    char* p = (char*)d_ws;
    _Float16* h      = (_Float16*)p; p += (size_t)N_NODES * OUT_CH * 2;  // 12.8 MB
    float* alpha_src = (float*)p;  p += (size_t)N_NODES * HEADS * 4;     // 1.6 MB
    float* alpha_dst = (float*)p;  p += (size_t)N_NODES * HEADS * 4;     // 1.6 MB
    float* wsd       = (float*)p;  p += (size_t)8 * IN_CH * 4;           // 4 KB
    int*   deg       = (int*)p;    p += (size_t)N_NODES * 4;
    int*   ptr       = (int*)p;    p += (size_t)(N_NODES + 4) * 4;
    int*   rank      = (int*)p;    p += (size_t)N_EDGES * 4;             // 6.4 MB
    int*   blockSums = (int*)p;    p += (size_t)((SCAN_BLOCKS + 3) & ~3) * 4;
    int*   blockOffs = (int*)p;    p += (size_t)((SCAN_BLOCKS + 3) & ~3) * 4;
    long long* csr   = (long long*)p;                                    // 12.8 MB

    hipMemsetAsync(deg, 0, (size_t)N_NODES * sizeof(int), stream);

    wsd_kernel<<<1, 128, 0, stream>>>(W, a, wsd);
    hist_rank_kernel<<<(N_EDGES + 255) / 256, 256, 0, stream>>>(ei, deg, rank);
    gemm_alpha_kernel<<<(N_NODES + 127) / 128, 256, 0, stream>>>(x, W, wsd, h, alpha_src, alpha_dst);
    scan_reduce_kernel<<<SCAN_BLOCKS, 256, 0, stream>>>(deg, blockSums);
    scan_blocksums_kernel<<<1, 512, 0, stream>>>(blockSums, blockOffs, ptr);
    scan_final_kernel<<<SCAN_BLOCKS, 256, 0, stream>>>(deg, blockOffs, ptr);
    fill_kernel<<<(N_EDGES + 255) / 256, 256, 0, stream>>>(ei, ew, rank, ptr, csr);
    aggregate_kernel<<<(N_NODES + 3) / 4, 256, 0, stream>>>(
        ptr, (const int2*)csr, (const float4*)alpha_src, (const float4*)alpha_dst, h, out);
}

// Round 9
// 299.512 us; speedup vs baseline: 3.7666x; 1.0112x over previous
//
#include <hip/hip_runtime.h>
#include <math.h>

#define N_NODES 100000
#define N_EDGES 1600000
#define IN_CH 128
#define HEADS 4
#define HEAD_DIM 16
#define OUT_CH 64
#define NEG_SLOPE 0.2f
#define EPS 1e-8f
#define SCAN_BLOCKS ((N_NODES + 255) / 256)   // 391
#define NCOPY 8                                // one deg copy per XCD

typedef _Float16 f16x8 __attribute__((ext_vector_type(8)));
typedef _Float16 f16x4 __attribute__((ext_vector_type(4)));
typedef float    f32x4 __attribute__((ext_vector_type(4)));

// ---------------------------------------------------------------------------
// Prep: wsd[8][128] fp32 — w_s rows 0-3, w_d rows 4-7.
// ---------------------------------------------------------------------------
__global__ __launch_bounds__(128) void wsd_kernel(
    const float* __restrict__ W, const float* __restrict__ a,
    float* __restrict__ wsd)
{
    int k = threadIdx.x;   // 0..127
#pragma unroll
    for (int hd = 0; hd < 4; hd++) {
        float ss = 0.f, dd = 0.f;
#pragma unroll
        for (int c = 0; c < 16; c++) {
            float wv = W[(hd * 16 + c) * IN_CH + k];
            ss += a[hd * 32 + c] * wv;
            dd += a[hd * 32 + 16 + c] * wv;
        }
        wsd[hd * IN_CH + k] = ss;
        wsd[(4 + hd) * IN_CH + k] = dd;
    }
}

__device__ inline f16x8 cvt8(const float* p) {
    float4 lo = ((const float4*)p)[0];
    float4 hi = ((const float4*)p)[1];
    f16x8 f;
    f[0] = (_Float16)lo.x; f[1] = (_Float16)lo.y;
    f[2] = (_Float16)lo.z; f[3] = (_Float16)lo.w;
    f[4] = (_Float16)hi.x; f[5] = (_Float16)hi.y;
    f[6] = (_Float16)hi.z; f[7] = (_Float16)hi.w;
    return f;
}

// ---------------------------------------------------------------------------
// GEMM via MFMA 16x16x32 f16. Block = 4 waves x 32 nodes = 128 nodes.
// N-tile 4 carries alpha (wsd rows; cols 0-3 = a_src heads, 4-7 = a_dst).
// ---------------------------------------------------------------------------
__global__ __launch_bounds__(256) void gemm_alpha_kernel(
    const float* __restrict__ x,      // [N_NODES, 128]
    const float* __restrict__ W,      // [64, 128]
    const float* __restrict__ wsd,    // [8, 128]
    _Float16* __restrict__ h,         // [N_NODES, 64] fp16
    float* __restrict__ alpha_src,    // [N_NODES, 4]
    float* __restrict__ alpha_dst)    // [N_NODES, 4]
{
    const int wv = threadIdx.x >> 6;
    const int lane = threadIdx.x & 63;
    const int col = lane & 15;
    const int quad = lane >> 4;
    const int node_base = blockIdx.x * 128 + wv * 32;

    f16x8 bfrag[5][4];
#pragma unroll
    for (int nt = 0; nt < 4; nt++) {
        const float* src = W + (nt * 16 + col) * IN_CH;
#pragma unroll
        for (int ks = 0; ks < 4; ks++)
            bfrag[nt][ks] = cvt8(src + ks * 32 + quad * 8);
    }
    {
        const float* src = wsd + (col < 8 ? col : 0) * IN_CH;
#pragma unroll
        for (int ks = 0; ks < 4; ks++) {
            f16x8 f = cvt8(src + ks * 32 + quad * 8);
            if (col >= 8) {
                f16x8 z = {};
                f = z;
            }
            bfrag[4][ks] = f;
        }
    }

#pragma unroll
    for (int mt = 0; mt < 2; mt++) {
        int row_node = node_base + mt * 16 + col;
        int rn = row_node < N_NODES ? row_node : N_NODES - 1;
        const float* xrow = x + (long long)rn * IN_CH;

        f16x8 afrag[4];
#pragma unroll
        for (int ks = 0; ks < 4; ks++)
            afrag[ks] = cvt8(xrow + ks * 32 + quad * 8);

        f32x4 acc[5];
#pragma unroll
        for (int nt = 0; nt < 5; nt++) {
            f32x4 z = {0.f, 0.f, 0.f, 0.f};
            acc[nt] = z;
        }
#pragma unroll
        for (int ks = 0; ks < 4; ks++)
#pragma unroll
            for (int nt = 0; nt < 5; nt++)
                acc[nt] = __builtin_amdgcn_mfma_f32_16x16x32_f16(
                    afrag[ks], bfrag[nt][ks], acc[nt], 0, 0, 0);

#pragma unroll
        for (int r = 0; r < 4; r++) {
            int node = node_base + mt * 16 + quad * 4 + r;
            if (node < N_NODES) {
#pragma unroll
                for (int nt = 0; nt < 4; nt++)
                    h[(long long)node * OUT_CH + nt * 16 + col] = (_Float16)acc[nt][r];
                if (col < 4)      alpha_src[node * HEADS + col]     = acc[4][r];
                else if (col < 8) alpha_dst[node * HEADS + col - 4] = acc[4][r];
            }
        }
    }
}

// ---------------------------------------------------------------------------
// CSR build with XCD-split histogram:
//   hist: atomics into deg8[blockIdx&7][dst]  (XCD-local L2, no line bounce)
//   combine: off8[c][n] = prefix over copies; deg[n] = total
//   scan (3-phase) -> ptr
//   fill: slot = ptr[d] + off8[c][d] + rank[e]   (same grid => same c)
// ---------------------------------------------------------------------------
__global__ __launch_bounds__(256) void hist_rank_kernel(
    const int* __restrict__ ei, int* __restrict__ deg8, int* __restrict__ rank)
{
    int e = blockIdx.x * 256 + threadIdx.x;
    if (e >= N_EDGES) return;
    int c = blockIdx.x & (NCOPY - 1);
    rank[e] = atomicAdd(&deg8[c * N_NODES + ei[N_EDGES + e]], 1);
}

__global__ __launch_bounds__(256) void combine_kernel(
    const int* __restrict__ deg8, int* __restrict__ off8, int* __restrict__ deg)
{
    int n = blockIdx.x * 256 + threadIdx.x;
    if (n >= N_NODES) return;
    int run = 0;
#pragma unroll
    for (int c = 0; c < NCOPY; c++) {
        off8[c * N_NODES + n] = run;
        run += deg8[c * N_NODES + n];
    }
    deg[n] = run;
}

__global__ __launch_bounds__(256) void scan_reduce_kernel(
    const int* __restrict__ deg, int* __restrict__ blockSums)
{
    __shared__ int sdata[256];
    int t = threadIdx.x;
    int i = blockIdx.x * 256 + t;
    sdata[t] = (i < N_NODES) ? deg[i] : 0;
    __syncthreads();
    for (int off = 128; off > 0; off >>= 1) {
        if (t < off) sdata[t] += sdata[t + off];
        __syncthreads();
    }
    if (t == 0) blockSums[blockIdx.x] = sdata[0];
}

__global__ __launch_bounds__(512) void scan_blocksums_kernel(
    const int* __restrict__ blockSums, int* __restrict__ blockOffsets,
    int* __restrict__ ptr)
{
    __shared__ int part[512];
    int t = threadIdx.x;
    int v = (t < SCAN_BLOCKS) ? blockSums[t] : 0;
    part[t] = v;
    __syncthreads();
    for (int off = 1; off < 512; off <<= 1) {
        int xv = (t >= off) ? part[t - off] : 0;
        __syncthreads();
        part[t] += xv;
        __syncthreads();
    }
    if (t < SCAN_BLOCKS) blockOffsets[t] = part[t] - v;  // exclusive
    if (t == 0) ptr[N_NODES] = N_EDGES;
}

__global__ __launch_bounds__(256) void scan_final_kernel(
    const int* __restrict__ deg, const int* __restrict__ blockOffsets,
    int* __restrict__ ptr)
{
    __shared__ int part[256];
    int t = threadIdx.x;
    int i = blockIdx.x * 256 + t;
    int v = (i < N_NODES) ? deg[i] : 0;
    part[t] = v;
    __syncthreads();
    for (int off = 1; off < 256; off <<= 1) {
        int xv = (t >= off) ? part[t - off] : 0;
        __syncthreads();
        part[t] += xv;
        __syncthreads();
    }
    if (i < N_NODES) ptr[i] = blockOffsets[blockIdx.x] + part[t] - v;
}

__global__ __launch_bounds__(256) void fill_kernel(
    const int* __restrict__ ei, const float* __restrict__ ew,
    const int* __restrict__ rank, const int* __restrict__ ptr,
    const int* __restrict__ off8, long long* __restrict__ csr)
{
    int e = blockIdx.x * 256 + threadIdx.x;
    if (e >= N_EDGES) return;
    int c = blockIdx.x & (NCOPY - 1);
    int s = ei[e];
    int d = ei[N_EDGES + e];
    int idx = ptr[d] + off8[c * N_NODES + d] + rank[e];
    long long v = (long long)((unsigned long long)__float_as_uint(ew[e]) << 32)
                | (unsigned int)s;
    __builtin_nontemporal_store(v, &csr[idx]);   // skip write-allocate on scatter
}

// ---------------------------------------------------------------------------
// Aggregate v3: one wave per dst node, quarter-wave edge parallelism.
// ---------------------------------------------------------------------------
__global__ __launch_bounds__(256) void aggregate_kernel(
    const int* __restrict__ ptr,
    const int2* __restrict__ csr,
    const float4* __restrict__ alpha_src4,   // [N_NODES]
    const float4* __restrict__ alpha_dst4,   // [N_NODES]
    const _Float16* __restrict__ h,          // [N_NODES, 64]
    float* __restrict__ out)
{
    __shared__ float4 sev[4][64];   // per-wave ev4 staging
    __shared__ int    ssc[4][64];   // per-wave src staging

    const int wv = threadIdx.x >> 6;
    const int lane = threadIdx.x & 63;
    const int n = blockIdx.x * 4 + wv;
    if (n >= N_NODES) return;
    const int q = lane >> 4;          // quarter 0..3
    const int cg = lane & 15;         // channel group: ch 4*cg..4*cg+3
    const int hsel = cg >> 2;         // head of this channel group

    const int beg = ptr[n];
    const int end = ptr[n + 1];
    const float4 ad4 = alpha_dst4[n];

    float4 acc = make_float4(0.f, 0.f, 0.f, 0.f);
    float denom = 0.f;
    float4* sev_w = sev[wv];
    int* ssc_w = ssc[wv];

    for (int base = beg; base < end; base += 64) {
        int cnt = min(64, end - base);
        int s_l = 0;
        float4 e4 = make_float4(0.f, 0.f, 0.f, 0.f);
        if (lane < cnt) {
            int2 pr = csr[base + lane];
            s_l = pr.x;
            float w = __int_as_float(pr.y);
            float4 as = alpha_src4[s_l];
            float t0 = as.x + ad4.x; t0 = (t0 > 0.f ? t0 : NEG_SLOPE * t0) * w;
            float t1 = as.y + ad4.y; t1 = (t1 > 0.f ? t1 : NEG_SLOPE * t1) * w;
            float t2 = as.z + ad4.z; t2 = (t2 > 0.f ? t2 : NEG_SLOPE * t2) * w;
            float t3 = as.w + ad4.w; t3 = (t3 > 0.f ? t3 : NEG_SLOPE * t3) * w;
            e4 = make_float4(__expf(t0), __expf(t1), __expf(t2), __expf(t3));
        }
        sev_w[lane] = e4;         // intra-wave LDS, no barrier needed
        ssc_w[lane] = s_l;

        int iters = (cnt + 3) >> 2;
        for (int j0 = 0; j0 < iters; j0 += 2) {
            int idx0 = j0 * 4 + q;
            int idx1 = idx0 + 4;          // may pass cnt: contributes zero
            int s0 = ssc_w[idx0];
            int s1 = ssc_w[idx1];
            float ev0 = ((const float*)&sev_w[idx0])[hsel];
            float ev1 = ((const float*)&sev_w[idx1])[hsel];
            f16x4 h0 = *(const f16x4*)(h + s0 * OUT_CH + cg * 4);
            f16x4 h1 = *(const f16x4*)(h + s1 * OUT_CH + cg * 4);
            acc.x += ev0 * (float)h0[0] + ev1 * (float)h1[0];
            acc.y += ev0 * (float)h0[1] + ev1 * (float)h1[1];
            acc.z += ev0 * (float)h0[2] + ev1 * (float)h1[2];
            acc.w += ev0 * (float)h0[3] + ev1 * (float)h1[3];
            denom += ev0 + ev1;
        }
    }

    // combine the 4 quarters (xor butterfly)
    denom += __shfl_xor(denom, 16);
    denom += __shfl_xor(denom, 32);
    acc.x += __shfl_xor(acc.x, 16);  acc.x += __shfl_xor(acc.x, 32);
    acc.y += __shfl_xor(acc.y, 16);  acc.y += __shfl_xor(acc.y, 32);
    acc.z += __shfl_xor(acc.z, 16);  acc.z += __shfl_xor(acc.z, 32);
    acc.w += __shfl_xor(acc.w, 16);  acc.w += __shfl_xor(acc.w, 32);

    if (lane < 16) {
        float inv = 1.f / (denom + EPS);
        float4 r = make_float4(acc.x * inv, acc.y * inv, acc.z * inv, acc.w * inv);
        ((float4*)(out + (long long)n * OUT_CH))[cg] = r;
    }
}

extern "C" void kernel_launch(void* const* d_in, const int* in_sizes, int n_in,
                              void* d_out, int out_size, void* d_ws, size_t ws_size,
                              hipStream_t stream) {
    const float* x  = (const float*)d_in[0];
    const int*   ei = (const int*)d_in[1];     // int32 per harness contract
    const float* ew = (const float*)d_in[2];
    const float* W  = (const float*)d_in[3];
    const float* a  = (const float*)d_in[4];
    float* out = (float*)d_out;

    // workspace layout (all 16B-aligned)
    char* p = (char*)d_ws;
    _Float16* h      = (_Float16*)p; p += (size_t)N_NODES * OUT_CH * 2;  // 12.8 MB
    float* alpha_src = (float*)p;  p += (size_t)N_NODES * HEADS * 4;     // 1.6 MB
    float* alpha_dst = (float*)p;  p += (size_t)N_NODES * HEADS * 4;     // 1.6 MB
    float* wsd       = (float*)p;  p += (size_t)8 * IN_CH * 4;           // 4 KB
    int*   deg8      = (int*)p;    p += (size_t)NCOPY * N_NODES * 4;     // 3.2 MB
    int*   off8      = (int*)p;    p += (size_t)NCOPY * N_NODES * 4;     // 3.2 MB
    int*   deg       = (int*)p;    p += (size_t)N_NODES * 4;             // 0.4 MB
    int*   ptr       = (int*)p;    p += (size_t)(N_NODES + 4) * 4;       // 0.4 MB
    int*   rank      = (int*)p;    p += (size_t)N_EDGES * 4;             // 6.4 MB
    int*   blockSums = (int*)p;    p += (size_t)((SCAN_BLOCKS + 3) & ~3) * 4;
    int*   blockOffs = (int*)p;    p += (size_t)((SCAN_BLOCKS + 3) & ~3) * 4;
    long long* csr   = (long long*)p;                                    // 12.8 MB

    hipMemsetAsync(deg8, 0, (size_t)NCOPY * N_NODES * sizeof(int), stream);

    wsd_kernel<<<1, 128, 0, stream>>>(W, a, wsd);
    hist_rank_kernel<<<(N_EDGES + 255) / 256, 256, 0, stream>>>(ei, deg8, rank);
    gemm_alpha_kernel<<<(N_NODES + 127) / 128, 256, 0, stream>>>(x, W, wsd, h, alpha_src, alpha_dst);
    combine_kernel<<<(N_NODES + 255) / 256, 256, 0, stream>>>(deg8, off8, deg);
    scan_reduce_kernel<<<SCAN_BLOCKS, 256, 0, stream>>>(deg, blockSums);
    scan_blocksums_kernel<<<1, 512, 0, stream>>>(blockSums, blockOffs, ptr);
    scan_final_kernel<<<SCAN_BLOCKS, 256, 0, stream>>>(deg, blockOffs, ptr);
    fill_kernel<<<(N_EDGES + 255) / 256, 256, 0, stream>>>(ei, ew, rank, ptr, off8, csr);
    aggregate_kernel<<<(N_NODES + 3) / 4, 256, 0, stream>>>(
        ptr, (const int2*)csr, (const float4*)alpha_src, (const float4*)alpha_dst, h, out);
}